// Round 7
// baseline (198.746 us; speedup 1.0000x reference)
//
#include <hip/hip_runtime.h>

#define N_NODES 100000
#define N_EDGES 1600000
#define IN_DIM 128
#define OUT_DIM 32

#define FP_SCALE 64.0f            // fixed-point lsb = 1/64
#define FP_INV (1.0f / 64.0f)
#define FP_OFF 1024               // per-add field offset (makes increments >0)

// -------- kernel 1: support = X @ W (proven; unchanged) --------
__global__ __launch_bounds__(256) void gemm_support(
    const float* __restrict__ x, const float* __restrict__ w,
    float* __restrict__ support) {
  __shared__ float ws[IN_DIM][OUT_DIM];
  __shared__ float xs[8][IN_DIM];
  const int tid = threadIdx.x;

  for (int i = tid; i < IN_DIM * OUT_DIM; i += 256)
    ws[i / OUT_DIM][i % OUT_DIM] = w[i];

  const int row0 = blockIdx.x * 8;
  for (int i = tid; i < 8 * IN_DIM; i += 256) {
    const int r = i / IN_DIM, k = i % IN_DIM;
    const int row = row0 + r;
    xs[r][k] = (row < N_NODES) ? x[(long long)row * IN_DIM + k] : 0.f;
  }
  __syncthreads();

  const int r = tid >> 5;
  const int c = tid & 31;
  const int row = row0 + r;
  if (row >= N_NODES) return;

  float acc = 0.f;
#pragma unroll
  for (int k = 0; k < IN_DIM; ++k)
    acc = fmaf(xs[r][k], ws[k][c], acc);
  support[(long long)row * OUT_DIM + c] = acc;
}

// -------- kernel 2: edge scatter, 4 dims per u64 fixed-point atomic --------
// 8 lanes per edge; lane l covers dims 4l..4l+3 packed as 4 x u16 fields.
// Field increment = round(v*s*64) + 1024 (strictly positive -> no borrow
// between fields). Lane 0 also counts the edge for offset correction.
__global__ __launch_bounds__(256) void scatter_u64(
    const int* __restrict__ rows, const int* __restrict__ cols,
    const float* __restrict__ vals, const float* __restrict__ support,
    unsigned long long* __restrict__ acc, unsigned int* __restrict__ cnt) {
  const long long gid = (long long)blockIdx.x * 256 + threadIdx.x;
  if (gid >= (long long)N_EDGES * 8) return;
  const int e = (int)(gid >> 3);
  const int l = (int)(gid & 7);          // dim-group 0..7
  const int r = rows[e];
  const int c = cols[e];
  const float v = vals[e];
  const float4 s = *(const float4*)(support + (long long)c * OUT_DIM + 4 * l);

  int i0 = __float2int_rn(v * s.x * FP_SCALE);
  int i1 = __float2int_rn(v * s.y * FP_SCALE);
  int i2 = __float2int_rn(v * s.z * FP_SCALE);
  int i3 = __float2int_rn(v * s.w * FP_SCALE);
  // clamp insurance: keeps every field increment in (0, 2048)
  i0 = min(max(i0, -1023), 1023);
  i1 = min(max(i1, -1023), 1023);
  i2 = min(max(i2, -1023), 1023);
  i3 = min(max(i3, -1023), 1023);

  const unsigned long long pk =
      (unsigned long long)(unsigned short)(FP_OFF + i0) |
      ((unsigned long long)(unsigned short)(FP_OFF + i1) << 16) |
      ((unsigned long long)(unsigned short)(FP_OFF + i2) << 32) |
      ((unsigned long long)(unsigned short)(FP_OFF + i3) << 48);

  atomicAdd(&acc[(long long)r * 8 + l], pk);
  if (l == 0) atomicAdd(&cnt[r], 1u);
}

// -------- kernel 3: finalize out = (fields - cnt*FP_OFF)/64 + bias ---------
__global__ __launch_bounds__(256) void finalize_u64(
    const unsigned long long* __restrict__ acc,
    const unsigned int* __restrict__ cnt, const float* __restrict__ bias,
    float* __restrict__ out) {
  const int i = blockIdx.x * 256 + threadIdx.x;   // one u64 (4 dims) each
  if (i >= N_NODES * 8) return;
  const unsigned long long a = acc[i];
  const int r = i >> 3;
  const int l = i & 7;
  const float corr = (float)((long long)cnt[r] * FP_OFF);
  const int d0 = 4 * l;
  float4 o;
  o.x = ((float)(int)(a & 0xFFFFu) - corr) * FP_INV + bias[d0 + 0];
  o.y = ((float)(int)((a >> 16) & 0xFFFFu) - corr) * FP_INV + bias[d0 + 1];
  o.z = ((float)(int)((a >> 32) & 0xFFFFu) - corr) * FP_INV + bias[d0 + 2];
  o.w = ((float)(int)((a >> 48) & 0xFFFFu) - corr) * FP_INV + bias[d0 + 3];
  *(float4*)(out + (long long)r * OUT_DIM + d0) = o;
}

extern "C" void kernel_launch(void* const* d_in, const int* in_sizes, int n_in,
                              void* d_out, int out_size, void* d_ws, size_t ws_size,
                              hipStream_t stream) {
  const float* x        = (const float*)d_in[0];
  const int*   adj_rows = (const int*)d_in[1];
  const int*   adj_cols = (const int*)d_in[2];
  const float* adj_vals = (const float*)d_in[3];
  const float* weight   = (const float*)d_in[4];
  const float* bias     = (const float*)d_in[5];
  float* out = (float*)d_out;

  // ---- workspace: support 12.8 MB | acc 6.4 MB | cnt 0.4 MB (contiguous) ----
  char* wsp = (char*)d_ws;
  float* support = (float*)wsp;                                   // 12,800,000 B
  unsigned long long* acc = (unsigned long long*)(wsp + 12800000); // 6,400,000 B
  unsigned int* cnt = (unsigned int*)(wsp + 19200000);             // 400,000 B

  // zero acc + cnt in one memset (adjacent)
  hipMemsetAsync(acc, 0, 6400000 + 400000, stream);
  gemm_support<<<(N_NODES + 7) / 8, 256, 0, stream>>>(x, weight, support);

  {
    const long long total = (long long)N_EDGES * 8;
    scatter_u64<<<(int)((total + 255) / 256), 256, 0, stream>>>(
        adj_rows, adj_cols, adj_vals, support, acc, cnt);
  }
  {
    const int total = N_NODES * 8;
    finalize_u64<<<(total + 255) / 256, 256, 0, stream>>>(acc, cnt, bias, out);
  }
}

// Round 8
// 134.069 us; speedup vs baseline: 1.4824x; 1.4824x over previous
//
#include <hip/hip_runtime.h>

#define N_NODES 100000
#define N_EDGES 1600000
#define IN_DIM 128
#define OUT_DIM 32

typedef _Float16 h2 __attribute__((ext_vector_type(2)));

// -------- kernel 1: support(fp16) = X @ W ; also zeroes out_h --------------
// 12500 blocks x 8 rows (exact: 12500*8 = 100000, no guards).
__global__ __launch_bounds__(256) void gemm_support(
    const float* __restrict__ x, const float* __restrict__ w,
    _Float16* __restrict__ support, unsigned* __restrict__ out_h_words) {
  __shared__ float ws[IN_DIM][OUT_DIM];   // 16 KB
  __shared__ float xs[8][IN_DIM];         // 4 KB
  const int tid = threadIdx.x;

  // stage W: 4096 floats = 1024 float4, coalesced, conflict-free LDS stores
  {
    const float4* w4 = (const float4*)w;
    float4* ws4 = (float4*)&ws[0][0];
    for (int i = tid; i < IN_DIM * OUT_DIM / 4; i += 256) ws4[i] = w4[i];
  }
  // stage 8 rows of x: 1024 floats = 256 float4, one per thread
  const int row0 = blockIdx.x * 8;
  {
    const float4* x4 = (const float4*)(x + (long long)row0 * IN_DIM);
    float4* xs4 = (float4*)&xs[0][0];
    xs4[tid] = x4[tid];
  }
  __syncthreads();

  const int r = tid >> 5;
  const int c = tid & 31;
  float acc = 0.f;
#pragma unroll
  for (int k = 0; k < IN_DIM; ++k)
    acc = fmaf(xs[r][k], ws[k][c], acc);
  support[(long long)(row0 + r) * OUT_DIM + c] = (_Float16)acc;

  // fused zero of out_h (fp16 accumulator): 1.6M u32 words, threads 0..3.2M
  const int g = blockIdx.x * 256 + tid;
  if (g < N_NODES * OUT_DIM / 2) out_h_words[g] = 0u;
}

// -------- packed v2f16 atomic add (HW fadd; CAS fallback) --------
__device__ __forceinline__ void pk_atomic_add_h2(h2* p, h2 v) {
#if __has_builtin(__builtin_amdgcn_global_atomic_fadd_v2f16)
  __builtin_amdgcn_global_atomic_fadd_v2f16(
      (__attribute__((address_space(1))) h2*)p, v);
#else
  unsigned* pu = (unsigned*)p;
  unsigned old = *pu;
  while (true) {
    h2 cur = __builtin_bit_cast(h2, old);
    h2 nv = cur + v;
    unsigned n = __builtin_bit_cast(unsigned, nv);
    unsigned r = atomicCAS(pu, old, n);
    if (r == old) break;
    old = r;
  }
#endif
}

// -------- kernel 2: edge-parallel scatter, fp16 support, pk-f16 atomics ----
// 16 lanes per edge, 2 dims per lane: 25.6M 4B atomic ops (op-roofline form).
__global__ __launch_bounds__(256) void scatter_h2(
    const int* __restrict__ rows, const int* __restrict__ cols,
    const float* __restrict__ vals, const _Float16* __restrict__ support,
    h2* __restrict__ out_h) {
  const long long gid = (long long)blockIdx.x * 256 + threadIdx.x;
  if (gid >= (long long)N_EDGES * 16) return;
  const int e = (int)(gid >> 4);
  const int l = (int)(gid & 15);          // dim-pair index 0..15
  const int r = rows[e];
  const int c = cols[e];
  const float v = vals[e];
  const h2 s = *(const h2*)(support + (long long)c * OUT_DIM + 2 * l);
  h2 inc = { (_Float16)(v * (float)s[0]), (_Float16)(v * (float)s[1]) };
  pk_atomic_add_h2(out_h + (long long)r * 16 + l, inc);
}

// -------- kernel 3: finalize out = fp32(out_h) + bias ----------------------
__global__ __launch_bounds__(256) void finalize_h(
    const h2* __restrict__ out_h, const float* __restrict__ bias,
    float* __restrict__ out) {
  const int i = blockIdx.x * 256 + threadIdx.x;     // 8-elem group index
  if (i >= N_NODES * OUT_DIM / 8) return;
  const h2* src = out_h + i * 4;
  float4 a, b;
  h2 p0 = src[0], p1 = src[1], p2 = src[2], p3 = src[3];
  const int d0 = (i * 8) & 31;                      // dims d0..d0+7
  a.x = (float)p0[0] + bias[d0 + 0];
  a.y = (float)p0[1] + bias[d0 + 1];
  a.z = (float)p1[0] + bias[d0 + 2];
  a.w = (float)p1[1] + bias[d0 + 3];
  b.x = (float)p2[0] + bias[d0 + 4];
  b.y = (float)p2[1] + bias[d0 + 5];
  b.z = (float)p3[0] + bias[d0 + 6];
  b.w = (float)p3[1] + bias[d0 + 7];
  float4* dst = (float4*)(out + (long long)i * 8);
  dst[0] = a;
  dst[1] = b;
}

extern "C" void kernel_launch(void* const* d_in, const int* in_sizes, int n_in,
                              void* d_out, int out_size, void* d_ws, size_t ws_size,
                              hipStream_t stream) {
  const float* x        = (const float*)d_in[0];
  const int*   adj_rows = (const int*)d_in[1];
  const int*   adj_cols = (const int*)d_in[2];
  const float* adj_vals = (const float*)d_in[3];
  const float* weight   = (const float*)d_in[4];
  const float* bias     = (const float*)d_in[5];
  float* out = (float*)d_out;

  // ---- workspace: support fp16 (6.4 MB) + out_h fp16 (6.4 MB) ----
  char* wsp = (char*)d_ws;
  _Float16* support = (_Float16*)wsp;               // 6,400,000 B
  h2* out_h = (h2*)(wsp + 6400000);                 // 6,400,000 B

  // gemm also zeroes out_h (no memset dispatch)
  gemm_support<<<N_NODES / 8, 256, 0, stream>>>(x, weight, support,
                                                (unsigned*)out_h);
  {
    const long long total = (long long)N_EDGES * 16;
    scatter_h2<<<(int)((total + 255) / 256), 256, 0, stream>>>(
        adj_rows, adj_cols, adj_vals, support, out_h);
  }
  {
    const int total = N_NODES * OUT_DIM / 8;
    finalize_h<<<(total + 255) / 256, 256, 0, stream>>>(out_h, bias, out);
  }
}

// Round 9
// 118.594 us; speedup vs baseline: 1.6759x; 1.1305x over previous
//
#include <hip/hip_runtime.h>

#define N_NODES 100000
#define N_EDGES 1600000
#define IN_DIM 128
#define OUT_DIM 32

typedef _Float16 h2 __attribute__((ext_vector_type(2)));
typedef _Float16 h4 __attribute__((ext_vector_type(4)));

#define FMA4(acc, s, wv)                  \
  acc.x = fmaf(s, wv.x, acc.x);           \
  acc.y = fmaf(s, wv.y, acc.y);           \
  acc.z = fmaf(s, wv.z, acc.z);           \
  acc.w = fmaf(s, wv.w, acc.w)

// -------- kernel 1: support(fp16) = X @ W, register-blocked ---------------
// 64 rows/block, 256 threads: thread (rr,cc) computes rows {2rr,2rr+1} x
// cols {4cc..4cc+3} via float4 LDS reads (padded, conflict-clean layouts).
// Also zeroes out_h (one uint4 per thread).
__global__ __launch_bounds__(256) void gemm_support(
    const float* __restrict__ x, const float* __restrict__ w,
    _Float16* __restrict__ support, uint4* __restrict__ out_h_vec) {
  __shared__ float xs[64][132];        // 33,792 B (pad 132: 2-way max)
  __shared__ float w4[8][129][4];      // 16,512 B (pad 129: perfect spread)
  const int t = threadIdx.x;
  const long long row0 = (long long)blockIdx.x * 64;

  // stage W transposed into float4-of-cols layout: w4[c/4][k][c%4]
  for (int i = t; i < IN_DIM * OUT_DIM; i += 256) {
    const int k = i >> 5, c = i & 31;
    w4[c >> 2][k][c & 3] = w[i];
  }
  // stage 64 rows of x as float4 (coalesced)
  for (int j = t; j < 64 * (IN_DIM / 4); j += 256) {
    const int r = j >> 5;              // 0..63
    const int f = j & 31;              // float4 index within row
    const long long row = row0 + r;
    float4 v = (row < N_NODES) ? ((const float4*)x)[row * (IN_DIM / 4) + f]
                               : make_float4(0.f, 0.f, 0.f, 0.f);
    *(float4*)&xs[r][f * 4] = v;
  }
  __syncthreads();

  const int rr = t >> 3;   // 0..31
  const int cc = t & 7;    // 0..7
  float4 a0 = make_float4(0.f, 0.f, 0.f, 0.f);
  float4 a1 = make_float4(0.f, 0.f, 0.f, 0.f);
#pragma unroll
  for (int k4 = 0; k4 < IN_DIM / 4; ++k4) {
    const int k = k4 * 4;
    const float4 xv0 = *(const float4*)&xs[2 * rr][k];
    const float4 xv1 = *(const float4*)&xs[2 * rr + 1][k];
    const float4 w0 = *(const float4*)&w4[cc][k][0];
    const float4 w1 = *(const float4*)&w4[cc][k + 1][0];
    const float4 w2 = *(const float4*)&w4[cc][k + 2][0];
    const float4 w3 = *(const float4*)&w4[cc][k + 3][0];
    FMA4(a0, xv0.x, w0); FMA4(a0, xv0.y, w1);
    FMA4(a0, xv0.z, w2); FMA4(a0, xv0.w, w3);
    FMA4(a1, xv1.x, w0); FMA4(a1, xv1.y, w1);
    FMA4(a1, xv1.z, w2); FMA4(a1, xv1.w, w3);
  }

  const long long r0 = row0 + 2 * rr;
  if (r0 < N_NODES) {
    h4 o = { (_Float16)a0.x, (_Float16)a0.y, (_Float16)a0.z, (_Float16)a0.w };
    *(h4*)(support + r0 * OUT_DIM + 4 * cc) = o;
  }
  const long long r1 = r0 + 1;
  if (r1 < N_NODES) {
    h4 o = { (_Float16)a1.x, (_Float16)a1.y, (_Float16)a1.z, (_Float16)a1.w };
    *(h4*)(support + r1 * OUT_DIM + 4 * cc) = o;
  }

  // fused zero of out_h: 400,000 uint4 (6.4 MB), 1563*256 = 400,128 threads
  const int g = blockIdx.x * 256 + t;
  if (g < N_NODES * OUT_DIM * 2 / 16) out_h_vec[g] = make_uint4(0, 0, 0, 0);
}

// -------- packed v2f16 atomic add (HW fadd; CAS fallback) --------
__device__ __forceinline__ void pk_atomic_add_h2(h2* p, h2 v) {
#if __has_builtin(__builtin_amdgcn_global_atomic_fadd_v2f16)
  __builtin_amdgcn_global_atomic_fadd_v2f16(
      (__attribute__((address_space(1))) h2*)p, v);
#else
  unsigned* pu = (unsigned*)p;
  unsigned old = *pu;
  while (true) {
    h2 cur = __builtin_bit_cast(h2, old);
    h2 nv = cur + v;
    unsigned n = __builtin_bit_cast(unsigned, nv);
    unsigned r = atomicCAS(pu, old, n);
    if (r == old) break;
    old = r;
  }
#endif
}

// -------- kernel 2: edge-parallel scatter, pk-f16 atomics (op roofline) ----
// grid exactly N_EDGES*16/256 = 100,000 blocks; no guard needed.
__global__ __launch_bounds__(256) void scatter_h2(
    const int* __restrict__ rows, const int* __restrict__ cols,
    const float* __restrict__ vals, const _Float16* __restrict__ support,
    h2* __restrict__ out_h) {
  const long long gid = (long long)blockIdx.x * 256 + threadIdx.x;
  const int e = (int)(gid >> 4);
  const int l = (int)(gid & 15);          // dim-pair index 0..15
  const int r = rows[e];
  const int c = cols[e];
  const float v = vals[e];
  const h2 s = *(const h2*)(support + (long long)c * OUT_DIM + 2 * l);
  h2 inc = { (_Float16)(v * (float)s[0]), (_Float16)(v * (float)s[1]) };
  pk_atomic_add_h2(out_h + (long long)r * 16 + l, inc);
}

// -------- kernel 3: finalize out = fp32(out_h) + bias ----------------------
__global__ __launch_bounds__(256) void finalize_h(
    const h2* __restrict__ out_h, const float* __restrict__ bias,
    float* __restrict__ out) {
  const int i = blockIdx.x * 256 + threadIdx.x;     // 8-elem group index
  if (i >= N_NODES * OUT_DIM / 8) return;
  const h2* src = out_h + i * 4;
  float4 a, b;
  h2 p0 = src[0], p1 = src[1], p2 = src[2], p3 = src[3];
  const int d0 = (i * 8) & 31;                      // dims d0..d0+7
  a.x = (float)p0[0] + bias[d0 + 0];
  a.y = (float)p0[1] + bias[d0 + 1];
  a.z = (float)p1[0] + bias[d0 + 2];
  a.w = (float)p1[1] + bias[d0 + 3];
  b.x = (float)p2[0] + bias[d0 + 4];
  b.y = (float)p2[1] + bias[d0 + 5];
  b.z = (float)p3[0] + bias[d0 + 6];
  b.w = (float)p3[1] + bias[d0 + 7];
  float4* dst = (float4*)(out + (long long)i * 8);
  dst[0] = a;
  dst[1] = b;
}

extern "C" void kernel_launch(void* const* d_in, const int* in_sizes, int n_in,
                              void* d_out, int out_size, void* d_ws, size_t ws_size,
                              hipStream_t stream) {
  const float* x        = (const float*)d_in[0];
  const int*   adj_rows = (const int*)d_in[1];
  const int*   adj_cols = (const int*)d_in[2];
  const float* adj_vals = (const float*)d_in[3];
  const float* weight   = (const float*)d_in[4];
  const float* bias     = (const float*)d_in[5];
  float* out = (float*)d_out;

  // ---- workspace: support fp16 (6.4 MB) + out_h fp16 (6.4 MB) ----
  char* wsp = (char*)d_ws;
  _Float16* support = (_Float16*)wsp;               // 6,400,000 B
  h2* out_h = (h2*)(wsp + 6400000);                 // 6,400,000 B

  // gemm also zeroes out_h (no memset dispatch)
  gemm_support<<<(N_NODES + 63) / 64, 256, 0, stream>>>(
      x, weight, support, (uint4*)out_h);
  {
    const long long total = (long long)N_EDGES * 16;
    scatter_h2<<<(int)(total / 256), 256, 0, stream>>>(
        adj_rows, adj_cols, adj_vals, support, out_h);
  }
  {
    const int total = N_NODES * OUT_DIM / 8;
    finalize_h<<<(total + 255) / 256, 256, 0, stream>>>(out_h, bias, out);
  }
}